// Round 6
// baseline (223.462 us; speedup 1.0000x reference)
//
#include <hip/hip_runtime.h>
#include <math.h>

#define KS    31
#define PADV  15
#define IMG   320
#define NOUT  289          // valid centered outputs (i in [15, 304))
#define TB    8            // 8x8 output pixels per block
#define TROWS 38           // TB + KS - 1
#define TSTR  39           // padded LDS row stride (odd -> conflict-free)
#define NTH   180
#define TABSTR 992         // 32 rows x 31 cols (row 31 = zeros)

__device__ __forceinline__ unsigned int ordkey(float f) {
    unsigned int b = __float_as_uint(f);
    return (b & 0x80000000u) ? ~b : (b | 0x80000000u);
}
__device__ __forceinline__ float ordval(unsigned int k) {
    unsigned int b = (k & 0x80000000u) ? (k & 0x7FFFFFFFu) : ~k;
    return __uint_as_float(b);
}

__global__ void init_mm(unsigned int* mm) {
    mm[0] = 0xFFFFFFFFu;   // running-min key
    mm[1] = 0u;            // running-max key
}

// ---- per-theta (env, phi) table: w(t,f,tap) = env * cos_rev(f0 * phi) ----
__global__ __launch_bounds__(256) void build_eftab(float2* __restrict__ tab) {
    const int t = blockIdx.x;
    const float th = ((float)t / 180.0f) * 3.14159265358979323846f;
    float st, ct;
    sincosf(th, &st, &ct);
    float2* base = tab + (size_t)t * TABSTR;
    for (int e = threadIdx.x; e < TABSTR; e += 256) {
        int dy = e / KS, dx = e - dy * KS;    // dy in 0..31
        float2 v = make_float2(0.0f, 0.0f);
        if (dy < KS) {
            float y = (float)(dy - PADV);
            float x = (float)(dx - PADV);
            float x_t = fmaf(x,  ct, y * st);
            float y_t = fmaf(-x, st, y * ct);
            float gamma = fmaf(0.04f, fabsf(y_t), 1.0f);     // 1 + 0.6|y_t|/15
            float gyt = gamma * y_t;
            float env = expf(-fmaf(x_t, x_t, gyt * gyt) * (1.0f / 72.0f));
            float phi = fmaf(x_t * y_t, (1.0f / 45.0f), x_t); // f_local*x_t = f0*phi
            v = make_float2(env, phi);
        }
        base[e] = v;
    }
}

// 256 threads = 64 pixels x 4 row-parts. Part q handles rows q*8..q*8+7
// (row 31 has env==0 in the table; only its LDS address needs clamping).
__global__ __launch_bounds__(256, 4) void gabor_conv(
    const float* __restrict__ fp, const int* __restrict__ fmap,
    const int* __restrict__ tmap, const float2* __restrict__ tab,
    float* __restrict__ out, unsigned int* __restrict__ mm)
{
    __shared__ float tile[TROWS * TSTR];
    const int bh = blockIdx.y * TB;
    const int bw = blockIdx.x * TB;
    const int tid = threadIdx.x;

    for (int i = tid; i < TROWS * TSTR; i += 256) {
        int r = i / TSTR, c = i - r * TSTR;
        int gr = bh + r, gc = bw + c;
        tile[i] = (gr < IMG && gc < IMG) ? fp[gr * IMG + gc] : 0.0f;
    }
    __syncthreads();

    const int pixel = tid >> 2, part = tid & 3;
    const int px = pixel & 7, py = pixel >> 3;
    const int oy = bh + py, ox = bw + px;
    const bool valid = (oy < NOUT) && (ox < NOUT);

    float acc0 = 0.0f, acc1 = 0.0f;
    if (valid) {
        const int iy = oy + PADV, ix = ox + PADV;
        const int theta = tmap[iy * IMG + ix];
        const float f0 = 0.025f + 0.0015f * (float)fmap[iy * IMG + ix];
        const int r0 = part * 8;
        const float2* __restrict__ efb = tab + (size_t)theta * TABSTR + r0 * KS;

        #pragma unroll
        for (int r = 0; r < 8; ++r) {
            const int dy  = r0 + r;
            const int dya = (dy > 30) ? 30 : dy;       // LDS addr clamp (dy==31 only)
            const float* trow = &tile[(py + dya) * TSTR + px];
            const float2* ef = efb + r * KS;
            #pragma unroll
            for (int c = 0; c < KS; ++c) {
                float2 w2 = ef[c];
                float cc = __builtin_amdgcn_cosf(f0 * w2.y);  // cos(2*pi*f_local*x_t)
                float w  = w2.x * cc;
                if (c & 1) acc1 = fmaf(trow[c], w, acc1);
                else       acc0 = fmaf(trow[c], w, acc0);
            }
        }
    }

    // combine the 4 row-parts (adjacent lanes) of each pixel
    float v = acc0 + acc1;
    v += __shfl_xor(v, 1, 64);
    v += __shfl_xor(v, 2, 64);

    float vmin = INFINITY, vmax = -INFINITY;
    if (valid && part == 0) {
        out[(oy + PADV) * IMG + (ox + PADV)] = v;
        vmin = v; vmax = v;
    }
    for (int off = 32; off; off >>= 1) {
        vmin = fminf(vmin, __shfl_down(vmin, off, 64));
        vmax = fmaxf(vmax, __shfl_down(vmax, off, 64));
    }
    if ((tid & 63) == 0) {
        atomicMin(&mm[0], ordkey(vmin));
        atomicMax(&mm[1], ordkey(vmax));
    }
}

__global__ __launch_bounds__(256) void border_copy(
    const float* __restrict__ fp, float* __restrict__ out,
    unsigned int* __restrict__ mm)
{
    int p = blockIdx.x * 256 + threadIdx.x;
    float vmin = INFINITY, vmax = -INFINITY;
    if (p < IMG * IMG) {
        int i = p / IMG, j = p - i * IMG;
        bool inner = (i >= PADV) && (i < PADV + NOUT) && (j >= PADV) && (j < PADV + NOUT);
        if (!inner) {
            float v = fp[p];
            out[p] = v;
            vmin = v; vmax = v;
        }
    }
    for (int off = 32; off; off >>= 1) {
        vmin = fminf(vmin, __shfl_down(vmin, off, 64));
        vmax = fmaxf(vmax, __shfl_down(vmax, off, 64));
    }
    if ((threadIdx.x & 63) == 0) {
        atomicMin(&mm[0], ordkey(vmin));
        atomicMax(&mm[1], ordkey(vmax));
    }
}

__global__ __launch_bounds__(256) void finalize(
    float* __restrict__ out, const unsigned int* __restrict__ mm)
{
    int p = blockIdx.x * 256 + threadIdx.x;
    if (p >= IMG * IMG) return;
    float mn = ordval(mm[0]);
    float mx = ordval(mm[1]) - mn;       // max(out - min) == max0 - min0
    float v  = out[p] - mn;
    if (mx != 0.0f) v = v / mx * 100.0f;
    out[p] = (v > 55.0f) ? 100.0f : 0.0f;
}

extern "C" void kernel_launch(void* const* d_in, const int* in_sizes, int n_in,
                              void* d_out, int out_size, void* d_ws, size_t ws_size,
                              hipStream_t stream) {
    const float* fp   = (const float*)d_in[0];
    const int*   fmap = (const int*)d_in[1];
    const int*   tmap = (const int*)d_in[2];
    float* out = (float*)d_out;
    unsigned int* mm = (unsigned int*)d_ws;
    float2* tab = (float2*)((char*)d_ws + 256);   // 180*992*8 B = 1.43 MB

    hipLaunchKernelGGL(init_mm, dim3(1), dim3(1), 0, stream, mm);
    hipLaunchKernelGGL(build_eftab, dim3(NTH), dim3(256), 0, stream, tab);

    dim3 g((NOUT + TB - 1) / TB, (NOUT + TB - 1) / TB);   // 37 x 37
    hipLaunchKernelGGL(gabor_conv, g, dim3(256), 0, stream,
                       fp, fmap, tmap, tab, out, mm);

    int nblk = (IMG * IMG + 255) / 256;
    hipLaunchKernelGGL(border_copy, dim3(nblk), dim3(256), 0, stream, fp, out, mm);
    hipLaunchKernelGGL(finalize,    dim3(nblk), dim3(256), 0, stream, out, mm);
}

// Round 7
// 213.945 us; speedup vs baseline: 1.0445x; 1.0445x over previous
//
#include <hip/hip_runtime.h>
#include <math.h>

#define KS    31
#define KSP   32           // padded taps per row (col 31: env=0)
#define PADV  15
#define IMG   320
#define NOUT  289          // valid centered outputs (i in [15, 304))
#define TB    8            // 8x8 output pixels per block
#define TROWS 38           // TB + KS - 1
#define TSTR  39           // padded LDS row stride (odd -> conflict-free)
#define NTH   180
#define TABQ  (KSP * KSP)  // 1024 float2 per theta (row 31: zeros)

__device__ __forceinline__ unsigned int ordkey(float f) {
    unsigned int b = __float_as_uint(f);
    return (b & 0x80000000u) ? ~b : (b | 0x80000000u);
}
__device__ __forceinline__ float ordval(unsigned int k) {
    unsigned int b = (k & 0x80000000u) ? (k & 0x7FFFFFFFu) : ~k;
    return __uint_as_float(b);
}

__global__ void init_mm(unsigned int* mm) {
    mm[0] = 0xFFFFFFFFu;   // running-min key
    mm[1] = 0u;            // running-max key
}

// ---- per-theta (env, phi) table: w(t,f,tap) = env * cos_rev(f0 * phi) ----
__global__ __launch_bounds__(256) void build_eftab(float2* __restrict__ tab) {
    const int t = blockIdx.x;
    const float th = ((float)t / 180.0f) * 3.14159265358979323846f;
    float st, ct;
    sincosf(th, &st, &ct);
    float2* base = tab + (size_t)t * TABQ;
    for (int e = threadIdx.x; e < TABQ; e += 256) {
        int dy = e >> 5, dx = e & 31;
        float2 v = make_float2(0.0f, 0.0f);
        if (dy < KS && dx < KS) {
            float y = (float)(dy - PADV);
            float x = (float)(dx - PADV);
            float x_t = fmaf(x,  ct, y * st);
            float y_t = fmaf(-x, st, y * ct);
            float gamma = fmaf(0.04f, fabsf(y_t), 1.0f);      // 1 + 0.6|y_t|/15
            float gyt = gamma * y_t;
            float env = expf(-fmaf(x_t, x_t, gyt * gyt) * (1.0f / 72.0f));
            float phi = fmaf(x_t * y_t, (1.0f / 45.0f), x_t); // f_local*x_t = f0*phi
            v = make_float2(env, phi);
        }
        base[e] = v;
    }
}

// 256 threads = 64 pixels x 4 row-parts. Part q handles rows q*8..q*8+7
// (row 31 / col 31 have env==0; only the LDS row address needs clamping).
__global__ __launch_bounds__(256, 4) void gabor_conv(
    const float* __restrict__ fp, const int* __restrict__ fmap,
    const int* __restrict__ tmap, const float2* __restrict__ tab,
    float* __restrict__ out, unsigned int* __restrict__ mm)
{
    __shared__ float tile[TROWS * TSTR];
    const int bh = blockIdx.y * TB;
    const int bw = blockIdx.x * TB;
    const int tid = threadIdx.x;

    for (int i = tid; i < TROWS * TSTR; i += 256) {
        int r = i / TSTR, c = i - r * TSTR;
        int gr = bh + r, gc = bw + c;
        tile[i] = (gr < IMG && gc < IMG) ? fp[gr * IMG + gc] : 0.0f;
    }
    __syncthreads();

    const int pixel = tid >> 2, part = tid & 3;
    const int px = pixel & 7, py = pixel >> 3;
    const int oy = bh + py, ox = bw + px;
    const bool valid = (oy < NOUT) && (ox < NOUT);

    float acc0 = 0.0f, acc1 = 0.0f;
    if (valid) {
        const int iy = oy + PADV, ix = ox + PADV;
        const int theta = tmap[iy * IMG + ix];
        const float f0 = 0.025f + 0.0015f * (float)fmap[iy * IMG + ix];
        const int r0 = part * 8;
        const float2* __restrict__ efb = tab + (size_t)theta * TABQ + (size_t)r0 * KSP;

        #pragma unroll
        for (int r = 0; r < 8; ++r) {
            const int dy  = r0 + r;
            const int dya = (dy > 30) ? 30 : dy;       // LDS row clamp (dy==31 only)
            const float* trow = &tile[(py + dya) * TSTR + px];

            // batch the whole padded table row (256 B) into registers
            const float4* ef4 = (const float4*)(efb + (size_t)r * KSP);
            float4 tw[16];
            #pragma unroll
            for (int i = 0; i < 16; ++i) tw[i] = ef4[i];
            #pragma unroll
            for (int i = 0; i < 16; ++i)
                asm volatile("" : "+v"(tw[i].x), "+v"(tw[i].y),
                                  "+v"(tw[i].z), "+v"(tw[i].w));

            #pragma unroll
            for (int c = 0; c < KSP; ++c) {
                float env = (c & 1) ? tw[c >> 1].z : tw[c >> 1].x;
                float phi = (c & 1) ? tw[c >> 1].w : tw[c >> 1].y;
                float cc  = __builtin_amdgcn_cosf(f0 * phi);  // cos(2*pi*f_local*x_t)
                float w   = env * cc;                          // env==0 pads c=31, dy=31
                if (c & 1) acc1 = fmaf(trow[c], w, acc1);
                else       acc0 = fmaf(trow[c], w, acc0);
            }
        }
    }

    // combine the 4 row-parts (adjacent lanes) of each pixel
    float v = acc0 + acc1;
    v += __shfl_xor(v, 1, 64);
    v += __shfl_xor(v, 2, 64);

    float vmin = INFINITY, vmax = -INFINITY;
    if (valid && part == 0) {
        out[(oy + PADV) * IMG + (ox + PADV)] = v;
        vmin = v; vmax = v;
    }
    for (int off = 32; off; off >>= 1) {
        vmin = fminf(vmin, __shfl_down(vmin, off, 64));
        vmax = fmaxf(vmax, __shfl_down(vmax, off, 64));
    }
    if ((tid & 63) == 0) {
        atomicMin(&mm[0], ordkey(vmin));
        atomicMax(&mm[1], ordkey(vmax));
    }
}

__global__ __launch_bounds__(256) void border_copy(
    const float* __restrict__ fp, float* __restrict__ out,
    unsigned int* __restrict__ mm)
{
    int p = blockIdx.x * 256 + threadIdx.x;
    float vmin = INFINITY, vmax = -INFINITY;
    if (p < IMG * IMG) {
        int i = p / IMG, j = p - i * IMG;
        bool inner = (i >= PADV) && (i < PADV + NOUT) && (j >= PADV) && (j < PADV + NOUT);
        if (!inner) {
            float v = fp[p];
            out[p] = v;
            vmin = v; vmax = v;
        }
    }
    for (int off = 32; off; off >>= 1) {
        vmin = fminf(vmin, __shfl_down(vmin, off, 64));
        vmax = fmaxf(vmax, __shfl_down(vmax, off, 64));
    }
    if ((threadIdx.x & 63) == 0) {
        atomicMin(&mm[0], ordkey(vmin));
        atomicMax(&mm[1], ordkey(vmax));
    }
}

__global__ __launch_bounds__(256) void finalize(
    float* __restrict__ out, const unsigned int* __restrict__ mm)
{
    int p = blockIdx.x * 256 + threadIdx.x;
    if (p >= IMG * IMG) return;
    float mn = ordval(mm[0]);
    float mx = ordval(mm[1]) - mn;       // max(out - min) == max0 - min0
    float v  = out[p] - mn;
    if (mx != 0.0f) v = v / mx * 100.0f;
    out[p] = (v > 55.0f) ? 100.0f : 0.0f;
}

extern "C" void kernel_launch(void* const* d_in, const int* in_sizes, int n_in,
                              void* d_out, int out_size, void* d_ws, size_t ws_size,
                              hipStream_t stream) {
    const float* fp   = (const float*)d_in[0];
    const int*   fmap = (const int*)d_in[1];
    const int*   tmap = (const int*)d_in[2];
    float* out = (float*)d_out;
    unsigned int* mm = (unsigned int*)d_ws;
    float2* tab = (float2*)((char*)d_ws + 256);   // 180*1024*8 B = 1.47 MB

    hipLaunchKernelGGL(init_mm, dim3(1), dim3(1), 0, stream, mm);
    hipLaunchKernelGGL(build_eftab, dim3(NTH), dim3(256), 0, stream, tab);

    dim3 g((NOUT + TB - 1) / TB, (NOUT + TB - 1) / TB);   // 37 x 37
    hipLaunchKernelGGL(gabor_conv, g, dim3(256), 0, stream,
                       fp, fmap, tmap, tab, out, mm);

    int nblk = (IMG * IMG + 255) / 256;
    hipLaunchKernelGGL(border_copy, dim3(nblk), dim3(256), 0, stream, fp, out, mm);
    hipLaunchKernelGGL(finalize,    dim3(nblk), dim3(256), 0, stream, out, mm);
}

// Round 8
// 106.341 us; speedup vs baseline: 2.1014x; 2.0119x over previous
//
#include <hip/hip_runtime.h>
#include <math.h>

#define KS    31
#define KSP   32           // padded taps per row (col 31: env=0)
#define PADV  15
#define IMG   320
#define NOUT  289          // valid centered outputs (i in [15, 304))
#define TB    8            // 8x8 output pixels per block
#define TROWS 38           // TB + KS - 1
#define TSTR  39           // padded LDS row stride (odd -> conflict-free)
#define NTH   180
#define TABQ  (KSP * KSP)  // 1024 float2 per theta (row 31: zeros)
#define RBLK  128          // reduction blocks

// ---- per-theta (env, phi) table: w(t,f,tap) = env * cos_rev(f0 * phi) ----
__global__ __launch_bounds__(256) void build_eftab(float2* __restrict__ tab) {
    const int t = blockIdx.x;
    const float th = ((float)t / 180.0f) * 3.14159265358979323846f;
    float st, ct;
    sincosf(th, &st, &ct);
    float2* base = tab + (size_t)t * TABQ;
    for (int e = threadIdx.x; e < TABQ; e += 256) {
        int dy = e >> 5, dx = e & 31;
        float2 v = make_float2(0.0f, 0.0f);
        if (dy < KS && dx < KS) {
            float y = (float)(dy - PADV);
            float x = (float)(dx - PADV);
            float x_t = fmaf(x,  ct, y * st);
            float y_t = fmaf(-x, st, y * ct);
            float gamma = fmaf(0.04f, fabsf(y_t), 1.0f);      // 1 + 0.6|y_t|/15
            float gyt = gamma * y_t;
            float env = expf(-fmaf(x_t, x_t, gyt * gyt) * (1.0f / 72.0f));
            float phi = fmaf(x_t * y_t, (1.0f / 45.0f), x_t); // f_local*x_t = f0*phi
            v = make_float2(env, phi);
        }
        base[e] = v;
    }
}

// 256 threads = 64 pixels x 4 row-parts. Part q handles rows q*8..q*8+7
// (row 31 / col 31 have env==0; only the LDS row address needs clamping).
// NO atomics, NO min/max: pure conv + store.
__global__ __launch_bounds__(256, 4) void gabor_conv(
    const float* __restrict__ fp, const int* __restrict__ fmap,
    const int* __restrict__ tmap, const float2* __restrict__ tab,
    float* __restrict__ out)
{
    __shared__ float tile[TROWS * TSTR];
    const int bh = blockIdx.y * TB;
    const int bw = blockIdx.x * TB;
    const int tid = threadIdx.x;

    for (int i = tid; i < TROWS * TSTR; i += 256) {
        int r = i / TSTR, c = i - r * TSTR;
        int gr = bh + r, gc = bw + c;
        tile[i] = (gr < IMG && gc < IMG) ? fp[gr * IMG + gc] : 0.0f;
    }
    __syncthreads();

    const int pixel = tid >> 2, part = tid & 3;
    const int px = pixel & 7, py = pixel >> 3;
    const int oy = bh + py, ox = bw + px;
    const bool valid = (oy < NOUT) && (ox < NOUT);

    float acc0 = 0.0f, acc1 = 0.0f;
    if (valid) {
        const int iy = oy + PADV, ix = ox + PADV;
        const int theta = tmap[iy * IMG + ix];
        const float f0 = 0.025f + 0.0015f * (float)fmap[iy * IMG + ix];
        const int r0 = part * 8;
        const float2* __restrict__ efb = tab + (size_t)theta * TABQ + (size_t)r0 * KSP;

        #pragma unroll
        for (int r = 0; r < 8; ++r) {
            const int dy  = r0 + r;
            const int dya = (dy > 30) ? 30 : dy;       // LDS row clamp (dy==31 only)
            const float* trow = &tile[(py + dya) * TSTR + px];

            // batch the whole padded table row (256 B) into registers
            const float4* ef4 = (const float4*)(efb + (size_t)r * KSP);
            float4 tw[16];
            #pragma unroll
            for (int i = 0; i < 16; ++i) tw[i] = ef4[i];
            #pragma unroll
            for (int i = 0; i < 16; ++i)
                asm volatile("" : "+v"(tw[i].x), "+v"(tw[i].y),
                                  "+v"(tw[i].z), "+v"(tw[i].w));

            #pragma unroll
            for (int c = 0; c < KSP; ++c) {
                float env = (c & 1) ? tw[c >> 1].z : tw[c >> 1].x;
                float phi = (c & 1) ? tw[c >> 1].w : tw[c >> 1].y;
                float cc  = __builtin_amdgcn_cosf(f0 * phi);  // cos(2*pi*f_local*x_t)
                float w   = env * cc;                          // env==0 pads c=31, dy=31
                if (c & 1) acc1 = fmaf(trow[c], w, acc1);
                else       acc0 = fmaf(trow[c], w, acc0);
            }
        }
    }

    // combine the 4 row-parts (adjacent lanes) of each pixel
    float v = acc0 + acc1;
    v += __shfl_xor(v, 1, 64);
    v += __shfl_xor(v, 2, 64);

    if (valid && part == 0)
        out[(oy + PADV) * IMG + (ox + PADV)] = v;
}

__global__ __launch_bounds__(256) void border_copy(
    const float* __restrict__ fp, float* __restrict__ out)
{
    int p = blockIdx.x * 256 + threadIdx.x;
    if (p >= IMG * IMG) return;
    int i = p / IMG, j = p - i * IMG;
    bool inner = (i >= PADV) && (i < PADV + NOUT) && (j >= PADV) && (j < PADV + NOUT);
    if (!inner) out[p] = fp[p];
}

// ---- stage 1: grid-stride min/max over out -> per-block partials ----
__global__ __launch_bounds__(256) void reduce_partials(
    const float* __restrict__ out, float2* __restrict__ part)
{
    __shared__ float smin[4], smax[4];
    float vmin = INFINITY, vmax = -INFINITY;
    for (int p = blockIdx.x * 256 + threadIdx.x; p < IMG * IMG; p += RBLK * 256) {
        float v = out[p];
        vmin = fminf(vmin, v);
        vmax = fmaxf(vmax, v);
    }
    for (int off = 32; off; off >>= 1) {
        vmin = fminf(vmin, __shfl_down(vmin, off, 64));
        vmax = fmaxf(vmax, __shfl_down(vmax, off, 64));
    }
    const int wave = threadIdx.x >> 6;
    if ((threadIdx.x & 63) == 0) { smin[wave] = vmin; smax[wave] = vmax; }
    __syncthreads();
    if (threadIdx.x == 0) {
        vmin = fminf(fminf(smin[0], smin[1]), fminf(smin[2], smin[3]));
        vmax = fmaxf(fmaxf(smax[0], smax[1]), fmaxf(smax[2], smax[3]));
        part[blockIdx.x] = make_float2(vmin, vmax);
    }
}

// ---- stage 2: single block reduces RBLK partials -> mm (plain floats) ----
__global__ __launch_bounds__(RBLK) void reduce_final(
    const float2* __restrict__ part, float* __restrict__ mm)
{
    __shared__ float smin[2], smax[2];
    float2 v = part[threadIdx.x];
    float vmin = v.x, vmax = v.y;
    for (int off = 32; off; off >>= 1) {
        vmin = fminf(vmin, __shfl_down(vmin, off, 64));
        vmax = fmaxf(vmax, __shfl_down(vmax, off, 64));
    }
    const int wave = threadIdx.x >> 6;
    if ((threadIdx.x & 63) == 0) { smin[wave] = vmin; smax[wave] = vmax; }
    __syncthreads();
    if (threadIdx.x == 0) {
        mm[0] = fminf(smin[0], smin[1]);
        mm[1] = fmaxf(smax[0], smax[1]);
    }
}

__global__ __launch_bounds__(256) void finalize(
    float* __restrict__ out, const float* __restrict__ mm)
{
    int p = blockIdx.x * 256 + threadIdx.x;
    if (p >= IMG * IMG) return;
    float mn = mm[0];
    float mx = mm[1] - mn;               // max(out - min) == max0 - min0
    float v  = out[p] - mn;
    if (mx != 0.0f) v = v / mx * 100.0f;
    out[p] = (v > 55.0f) ? 100.0f : 0.0f;
}

extern "C" void kernel_launch(void* const* d_in, const int* in_sizes, int n_in,
                              void* d_out, int out_size, void* d_ws, size_t ws_size,
                              hipStream_t stream) {
    const float* fp   = (const float*)d_in[0];
    const int*   fmap = (const int*)d_in[1];
    const int*   tmap = (const int*)d_in[2];
    float* out = (float*)d_out;

    float*  mm   = (float*)d_ws;                          // 2 floats
    float2* part = (float2*)((char*)d_ws + 256);          // RBLK float2
    float2* tab  = (float2*)((char*)d_ws + 4096);         // 180*1024*8 = 1.47 MB

    hipLaunchKernelGGL(build_eftab, dim3(NTH), dim3(256), 0, stream, tab);

    dim3 g((NOUT + TB - 1) / TB, (NOUT + TB - 1) / TB);   // 37 x 37
    hipLaunchKernelGGL(gabor_conv, g, dim3(256), 0, stream, fp, fmap, tmap, tab, out);

    int nblk = (IMG * IMG + 255) / 256;
    hipLaunchKernelGGL(border_copy,     dim3(nblk), dim3(256), 0, stream, fp, out);
    hipLaunchKernelGGL(reduce_partials, dim3(RBLK), dim3(256), 0, stream, out, part);
    hipLaunchKernelGGL(reduce_final,    dim3(1),    dim3(RBLK), 0, stream, part, mm);
    hipLaunchKernelGGL(finalize,        dim3(nblk), dim3(256), 0, stream, out, mm);
}